// Round 5
// baseline (4021.469 us; speedup 1.0000x reference)
//
#include <hip/hip_runtime.h>
#include <stdint.h>

typedef unsigned short u16;
typedef unsigned int u32;

__device__ __forceinline__ float bf2f(u16 h) { return __uint_as_float(((u32)h) << 16); }
__device__ __forceinline__ u16 f2bf(float f) {
    u32 x = __float_as_uint(f);
    u32 r = x + 0x7FFFu + ((x >> 16) & 1u);
    return (u16)(r >> 16);
}

// ---- f32 -> bf16 stash copy ----
__global__ __launch_bounds__(256)
void compress_bf16(const float* __restrict__ src, u16* __restrict__ dst, int n) {
    int i = blockIdx.x * 256 + threadIdx.x;
    if (i < n) dst[i] = f2bf(src[i]);
}

// ---- Path A: combined scatter, both directions, full buffers ----
// aggm[dst] += xu[src]; aggu[src] += xm[dst]; one wave per edge, float2/lane.
template <int DEG>
__global__ __launch_bounds__(256)
void scatter_both(const float* __restrict__ xu, const float* __restrict__ xm,
                  const int* __restrict__ src, const int* __restrict__ dst,
                  float* __restrict__ aggu, float* __restrict__ aggm,
                  int* __restrict__ degu, int* __restrict__ degm,
                  int E, int nu, int nm) {
    const int l = threadIdx.x & 63;
    const int e = blockIdx.x * 4 + (threadIdx.x >> 6);
    if (e >= E) return;
    const int s = src[e], d = dst[e];
    if ((unsigned)s >= (unsigned)nu || (unsigned)d >= (unsigned)nm) return;
    float2 wu = ((const float2*)xu)[(size_t)s * 64 + l];
    float* pm = aggm + (size_t)d * 128 + 2 * l;
    atomicAdd(pm, wu.x);
    atomicAdd(pm + 1, wu.y);
    float2 wm = ((const float2*)xm)[(size_t)d * 64 + l];
    float* pu = aggu + (size_t)s * 128 + 2 * l;
    atomicAdd(pu, wm.x);
    atomicAdd(pu + 1, wm.y);
    if (DEG && l == 0) {
        atomicAdd(&degm[d], 1);
        atomicAdd(&degu[s], 1);
    }
}

// ---- Path C: chunked scatter + fused degree count ----
// SIDE=0: target = dst (movie agg, gather user-side feats)
// SIDE=1: target = src (user agg, gather movie-side feats)
// BF16: feat buffer is bf16 (the r_m stash) instead of f32.
template <int SIDE, int BF16>
__global__ __launch_bounds__(256)
void scatter_chunk(const void* __restrict__ featv, const int* __restrict__ src,
                   const int* __restrict__ dst, float* __restrict__ agg,
                   int* __restrict__ deg, int E, int lo, int hi, int gN) {
    const int l = threadIdx.x & 63;
    const int e = blockIdx.x * 4 + (threadIdx.x >> 6);
    if (e >= E) return;
    const int t = SIDE ? src[e] : dst[e];
    if (t < lo || t >= hi) return;
    const int g = SIDE ? dst[e] : src[e];
    if ((unsigned)g >= (unsigned)gN) return;
    float w0, w1;
    if (BF16) {
        const u32 p = ((const u32*)featv)[(size_t)g * 64 + l];  // 2 bf16
        w0 = __uint_as_float(p << 16);
        w1 = __uint_as_float(p & 0xFFFF0000u);
    } else {
        const float2 p = ((const float2*)featv)[(size_t)g * 64 + l];
        w0 = p.x; w1 = p.y;
    }
    float* p = agg + (size_t)(t - lo) * 128 + 2 * l;
    atomicAdd(p, w0);
    atomicAdd(p + 1, w1);
    if (l == 0) atomicAdd(&deg[t - lo], 1);
}

// ---- fused node update: out = [x + relu](agg/deg @ Wl + b + x @ Wr) ----
// v = [agg_mean(128) ; x(128)]; W_stack = [Wl ; Wr] (256x128) staged in 4
// quarters (32 KB) + 16 nodes staged once (16 KB). In-place safe (out may
// alias x): x rows staged to LDS before any store; node in exactly one block.
template <int RELU_RES>
__global__ __launch_bounds__(256)
void node_update(const float* __restrict__ x, const float* __restrict__ agg,
                 const int* __restrict__ deg,
                 const float* __restrict__ Wl, const float* __restrict__ Wr,
                 const float* __restrict__ bias,
                 float* __restrict__ out, int N) {
    __shared__ float sV[16][256];
    __shared__ float sW[64][128];
    const int tid = threadIdx.x;
    const int nj = tid & 127;
    const int half = tid >> 7;
    const int base = blockIdx.x * 16;

    for (int idx = tid; idx < 16 * 256; idx += 256) {
        int node = idx >> 8, k = idx & 255;
        int n = base + node;
        float v = 0.f;
        if (n < N) {
            if (k < 128) {
                int dg = deg[n];
                float inv = 1.0f / (float)(dg > 1 ? dg : 1);
                v = agg[(size_t)n * 128 + k] * inv;
            } else {
                v = x[(size_t)n * 128 + (k - 128)];
            }
        }
        sV[node][k] = v;
    }

    float acc[8];
#pragma unroll
    for (int i = 0; i < 8; ++i) acc[i] = 0.f;

    for (int q = 0; q < 4; ++q) {
        for (int idx = tid; idx < 64 * 128; idx += 256) {
            int k = idx >> 7, j = idx & 127;
            int row = q * 64 + k;
            sW[k][j] = (row < 128) ? Wl[row * 128 + j] : Wr[(row - 128) * 128 + j];
        }
        __syncthreads();
#pragma unroll 8
        for (int k = 0; k < 64; ++k) {
            float w = sW[k][nj];
#pragma unroll
            for (int n8 = 0; n8 < 8; ++n8)
                acc[n8] += sV[n8 * 2 + half][q * 64 + k] * w;
        }
        __syncthreads();
    }

    const float bj = bias[nj];
#pragma unroll
    for (int n8 = 0; n8 < 8; ++n8) {
        int n = base + n8 * 2 + half;
        if (n < N) {
            float h = acc[n8] + bj;
            float o = RELU_RES ? (sV[n8 * 2 + half][128 + nj] + fmaxf(h, 0.f)) : h;
            out[(size_t)n * 128 + nj] = o;
        }
    }
}

extern "C" void kernel_launch(void* const* d_in, const int* in_sizes, int n_in,
                              void* d_out, int out_size, void* d_ws, size_t ws_size,
                              hipStream_t stream) {
    const int nu = in_sizes[0] / 128;
    const int nm = in_sizes[1] / 128;
    const int E = in_sizes[2];

    const float* xu = (const float*)d_in[0];
    const float* xm = (const float*)d_in[1];
    const int* esrc = (const int*)d_in[2];
    const int* edst = (const int*)d_in[3];
    const float* Wl1_um = (const float*)d_in[4];
    const float* Wr1_um = (const float*)d_in[5];
    const float* Wl1_mu = (const float*)d_in[6];
    const float* Wr1_mu = (const float*)d_in[7];
    const float* Wl2_um = (const float*)d_in[8];
    const float* Wr2_um = (const float*)d_in[9];
    const float* Wl2_mu = (const float*)d_in[10];
    const float* Wr2_mu = (const float*)d_in[11];
    const float* b1_um = (const float*)d_in[12];
    const float* b1_mu = (const float*)d_in[13];
    const float* b2_um = (const float*)d_in[14];
    const float* b2_mu = (const float*)d_in[15];

    float* out_u = (float*)d_out;
    float* out_m = out_u + (size_t)nu * 128;
    char* ws = (char*)d_ws;
    const int sgrid = (E + 3) / 4;

    const size_t aggu_b = (size_t)nu * 512;
    const size_t aggm_b = (size_t)nm * 512;
    const size_t degu_b = (size_t)nu * 4;
    const size_t degm_b = (size_t)nm * 4;

    if (ws_size >= aggu_b + aggm_b + degu_b + degm_b) {
        // ===================== Path A: full f32 buffers =====================
        float* aggu = (float*)ws;
        float* aggm = (float*)(ws + aggu_b);
        int* degu = (int*)(ws + aggu_b + aggm_b);
        int* degm = (int*)(ws + aggu_b + aggm_b + degu_b);

        // layer 1 (reads d_in only; writes r_* into d_out)
        hipMemsetAsync(ws, 0, aggu_b + aggm_b + degu_b + degm_b, stream);
        scatter_both<1><<<sgrid, 256, 0, stream>>>(
            xu, xm, esrc, edst, aggu, aggm, degu, degm, E, nu, nm);
        node_update<1><<<(nm + 15) / 16, 256, 0, stream>>>(
            xm, aggm, degm, Wl1_um, Wr1_um, b1_um, out_m, nm);
        node_update<1><<<(nu + 15) / 16, 256, 0, stream>>>(
            xu, aggu, degu, Wl1_mu, Wr1_mu, b1_mu, out_u, nu);

        // layer 2: BOTH aggregations read r_u/r_m before any in-place update
        hipMemsetAsync(ws, 0, aggu_b + aggm_b, stream);
        scatter_both<0><<<sgrid, 256, 0, stream>>>(
            out_u, out_m, esrc, edst, aggu, aggm, degu, degm, E, nu, nm);
        node_update<0><<<(nm + 15) / 16, 256, 0, stream>>>(
            out_m, aggm, degm, Wl2_um, Wr2_um, b2_um, out_m, nm);   // in-place
        node_update<0><<<(nu + 15) / 16, 256, 0, stream>>>(
            out_u, aggu, degu, Wl2_mu, Wr2_mu, b2_mu, out_u, nu);   // in-place
    } else {
        // ============ Path C: chunked, bf16 r_m stash in d_ws ============
        // layout: [ rm_stash bf16 (nm*256 B) | agg chunk | deg chunk ]
        const size_t stash_b = (size_t)nm * 256;
        u16* rm_stash = (u16*)ws;
        long long avail = (long long)ws_size - (long long)stash_b;
        long long rows_ll = avail > 0 ? avail / 516 : 1;
        if (rows_ll < 1) rows_ll = 1;
        if (rows_ll > nu) rows_ll = nu;
        const int rows = (int)rows_ll;
        float* agg = (float*)(ws + stash_b);
        int* deg = (int*)(ws + stash_b + (size_t)rows * 512);

        auto run_side = [&](int SIDE, int BF16, int N, const void* feat,
                            const float* xbase, const float* Wl, const float* Wr,
                            const float* bias, float* outbase, int relu) {
            for (int lo = 0; lo < N; lo += rows) {
                int len = (N - lo) < rows ? (N - lo) : rows;
                hipMemsetAsync(agg, 0, (size_t)len * 512, stream);
                hipMemsetAsync(deg, 0, (size_t)len * 4, stream);
                if (SIDE == 0) {
                    if (BF16) scatter_chunk<0, 1><<<sgrid, 256, 0, stream>>>(
                        feat, esrc, edst, agg, deg, E, lo, lo + len, nu);
                    else scatter_chunk<0, 0><<<sgrid, 256, 0, stream>>>(
                        feat, esrc, edst, agg, deg, E, lo, lo + len, nu);
                } else {
                    if (BF16) scatter_chunk<1, 1><<<sgrid, 256, 0, stream>>>(
                        feat, esrc, edst, agg, deg, E, lo, lo + len, nm);
                    else scatter_chunk<1, 0><<<sgrid, 256, 0, stream>>>(
                        feat, esrc, edst, agg, deg, E, lo, lo + len, nm);
                }
                int ggrid = (len + 15) / 16;
                if (relu)
                    node_update<1><<<ggrid, 256, 0, stream>>>(
                        xbase + (size_t)lo * 128, agg, deg, Wl, Wr, bias,
                        outbase + (size_t)lo * 128, len);
                else
                    node_update<0><<<ggrid, 256, 0, stream>>>(
                        xbase + (size_t)lo * 128, agg, deg, Wl, Wr, bias,
                        outbase + (size_t)lo * 128, len);
            }
        };

        // layer 1
        run_side(0, 0, nm, xu, xm, Wl1_um, Wr1_um, b1_um, out_m, 1);
        run_side(1, 0, nu, xm, xu, Wl1_mu, Wr1_mu, b1_mu, out_u, 1);

        // stash r_m (bf16) into d_ws
        {
            int nf = nm * 128;
            compress_bf16<<<(nf + 255) / 256, 256, 0, stream>>>(out_m, rm_stash, nf);
        }

        // layer 2: movie phase first (reads r_u, overwrites out_m in-place;
        // r_m preserved in stash), then user phase (reads stash, overwrites
        // out_u in-place; all movie scatters already consumed r_u).
        run_side(0, 0, nm, out_u, out_m, Wl2_um, Wr2_um, b2_um, out_m, 0);
        run_side(1, 1, nu, rm_stash, out_u, Wl2_mu, Wr2_mu, b2_mu, out_u, 0);
    }
}

// Round 6
// 1621.116 us; speedup vs baseline: 2.4807x; 2.4807x over previous
//
#include <hip/hip_runtime.h>
#include <stdint.h>

// All tensors are float32 (confirmed round 4). Output = [out_u | out_m] f32.
// Strategy (round 6): CSR-based aggregation — no f32 atomics.
//   round-5 counters: scatter_both = 2x1690us, WRITE_SIZE 2.06 GB/dispatch
//   (atomic RMW evictions), VALUBusy 2.7%. CSR build is 2M int atomics;
//   aggregation becomes coalesced gather-reads fused into the node GEMM.

// ---- histogram of edge endpoints ----
__global__ __launch_bounds__(256)
void hist_kernel(const int* __restrict__ src, const int* __restrict__ dst,
                 int* __restrict__ cntu, int* __restrict__ cntm,
                 int E, int nu, int nm) {
    int e = blockIdx.x * 256 + threadIdx.x;
    if (e >= E) return;
    int s = src[e], d = dst[e];
    if ((unsigned)s < (unsigned)nu) atomicAdd(&cntu[s], 1);
    if ((unsigned)d < (unsigned)nm) atomicAdd(&cntm[d], 1);
}

// ---- single-block exclusive scan (16 elems/thread/chunk) ----
// On exit: off[0..n] = exclusive prefix (off[n]=total); cnt_cur[i] = off[i]
// (reused as the fill cursor).
__global__ __launch_bounds__(1024)
void scan_excl(int* __restrict__ cnt_cur, int* __restrict__ off, int n) {
    __shared__ int s[1024];
    __shared__ int carry_s;
    const int tid = threadIdx.x;
    if (tid == 0) carry_s = 0;
    __syncthreads();
    const int CH = 1024 * 16;
    for (int chunk = 0; chunk < n; chunk += CH) {
        int base = chunk + tid * 16;
        int v[16];
        int sum = 0;
#pragma unroll
        for (int k = 0; k < 16; ++k) {
            int i = base + k;
            v[k] = (i < n) ? cnt_cur[i] : 0;
            sum += v[k];
        }
        s[tid] = sum;
        __syncthreads();
        for (int d = 1; d < 1024; d <<= 1) {
            int t = (tid >= d) ? s[tid - d] : 0;
            __syncthreads();
            s[tid] += t;
            __syncthreads();
        }
        int run = carry_s + s[tid] - sum;   // exclusive prefix of this thread's first elem
#pragma unroll
        for (int k = 0; k < 16; ++k) {
            int i = base + k;
            if (i < n) { off[i] = run; cnt_cur[i] = run; }
            run += v[k];
        }
        __syncthreads();                    // all carry_s reads done
        if (tid == 1023) carry_s += s[1023];
        __syncthreads();
    }
    if (tid == 0) off[n] = carry_s;
}

// ---- CSR fill: nbrm[row of dst] = src ; nbru[row of src] = dst ----
__global__ __launch_bounds__(256)
void fill_kernel(const int* __restrict__ src, const int* __restrict__ dst,
                 int* __restrict__ curu, int* __restrict__ curm,
                 int* __restrict__ nbru, int* __restrict__ nbrm,
                 int E, int nu, int nm) {
    int e = blockIdx.x * 256 + threadIdx.x;
    if (e >= E) return;
    int s = src[e], d = dst[e];
    if ((unsigned)s >= (unsigned)nu || (unsigned)d >= (unsigned)nm) return;
    int pm = atomicAdd(&curm[d], 1);
    nbrm[pm] = s;
    int pu = atomicAdd(&curu[s], 1);
    nbru[pu] = d;
}

// ---- f32 copy (r_m stash) ----
__global__ __launch_bounds__(256)
void copy_f32(const float* __restrict__ src, float* __restrict__ dst, int n) {
    int i = blockIdx.x * 256 + threadIdx.x;
    if (i < n) dst[i] = src[i];
}

// ---- fused gather-mean + node update ----
// out = [x + relu](mean_{g in nbr(n)} feat[g] @ Wl + b + x @ Wr)
// Block = 256 threads, 16 nodes. Phase 1: two 128-thread groups gather
// neighbor rows (coalesced 512 B) with 4-way ILP and stage [mean ; x] into
// sV. Phase 2: 256-K GEMM with W_stack=[Wl;Wr] staged in 4 quarters (proven
// in round 5). In-place safe: x rows staged in LDS before out is stored and
// this kernel never gathers from `out`'s buffer.
template <int RELU_RES>
__global__ __launch_bounds__(256)
void fused_update(const float* __restrict__ feat, const float* __restrict__ x,
                  const int* __restrict__ off, const int* __restrict__ nbr,
                  const float* __restrict__ Wl, const float* __restrict__ Wr,
                  const float* __restrict__ bias,
                  float* __restrict__ out, int N) {
    __shared__ float sV[16][256];   // [node][k]: k<128 mean, k>=128 x
    __shared__ float sW[64][128];
    const int tid = threadIdx.x;
    const int nj = tid & 127;
    const int half = tid >> 7;
    const int base = blockIdx.x * 16;

    // phase 1: gather-mean (group `half` handles nodes i = half, half+2, ...)
    for (int i = half; i < 16; i += 2) {
        int n = base + i;
        if (n < N) {
            int b = off[n], e = off[n + 1];
            float a0 = 0.f, a1 = 0.f, a2 = 0.f, a3 = 0.f;
            int t = b;
            for (; t + 3 < e; t += 4) {
                int g0 = nbr[t], g1 = nbr[t + 1], g2 = nbr[t + 2], g3 = nbr[t + 3];
                a0 += feat[(size_t)g0 * 128 + nj];
                a1 += feat[(size_t)g1 * 128 + nj];
                a2 += feat[(size_t)g2 * 128 + nj];
                a3 += feat[(size_t)g3 * 128 + nj];
            }
            for (; t < e; ++t) a0 += feat[(size_t)nbr[t] * 128 + nj];
            int dg = e - b;
            float inv = 1.0f / (float)(dg > 1 ? dg : 1);
            sV[i][nj] = (a0 + a1 + a2 + a3) * inv;
            sV[i][128 + nj] = x[(size_t)n * 128 + nj];
        } else {
            sV[i][nj] = 0.f;
            sV[i][128 + nj] = 0.f;
        }
    }

    // phase 2: GEMM over K=256 in 4 staged quarters
    float acc[8];
#pragma unroll
    for (int i = 0; i < 8; ++i) acc[i] = 0.f;

    for (int q = 0; q < 4; ++q) {
        for (int idx = tid; idx < 64 * 128; idx += 256) {
            int k = idx >> 7, j = idx & 127;
            int row = q * 64 + k;
            sW[k][j] = (row < 128) ? Wl[row * 128 + j] : Wr[(row - 128) * 128 + j];
        }
        __syncthreads();            // sV complete (q==0) + sW quarter ready
#pragma unroll 8
        for (int k = 0; k < 64; ++k) {
            float w = sW[k][nj];
#pragma unroll
            for (int n8 = 0; n8 < 8; ++n8)
                acc[n8] += sV[n8 * 2 + half][q * 64 + k] * w;
        }
        __syncthreads();
    }

    const float bj = bias[nj];
#pragma unroll
    for (int n8 = 0; n8 < 8; ++n8) {
        int n = base + n8 * 2 + half;
        if (n < N) {
            float h = acc[n8] + bj;
            float o = RELU_RES ? (sV[n8 * 2 + half][128 + nj] + fmaxf(h, 0.f)) : h;
            out[(size_t)n * 128 + nj] = o;
        }
    }
}

extern "C" void kernel_launch(void* const* d_in, const int* in_sizes, int n_in,
                              void* d_out, int out_size, void* d_ws, size_t ws_size,
                              hipStream_t stream) {
    const int nu = in_sizes[0] / 128;
    const int nm = in_sizes[1] / 128;
    const int E = in_sizes[2];

    const float* xu = (const float*)d_in[0];
    const float* xm = (const float*)d_in[1];
    const int* esrc = (const int*)d_in[2];
    const int* edst = (const int*)d_in[3];
    const float* Wl1_um = (const float*)d_in[4];
    const float* Wr1_um = (const float*)d_in[5];
    const float* Wl1_mu = (const float*)d_in[6];
    const float* Wr1_mu = (const float*)d_in[7];
    const float* Wl2_um = (const float*)d_in[8];
    const float* Wr2_um = (const float*)d_in[9];
    const float* Wl2_mu = (const float*)d_in[10];
    const float* Wr2_mu = (const float*)d_in[11];
    const float* b1_um = (const float*)d_in[12];
    const float* b1_mu = (const float*)d_in[13];
    const float* b2_um = (const float*)d_in[14];
    const float* b2_mu = (const float*)d_in[15];

    float* out_u = (float*)d_out;
    float* out_m = out_u + (size_t)nu * 128;

    // ---- workspace layout (~19.2 MB; ws_size >= 62 MB confirmed round 5) ----
    int* cntu = (int*)d_ws;                    // nu   (histogram -> cursor)
    int* cntm = cntu + nu;                     // nm
    int* offu = cntm + nm;                     // nu+1
    int* offm = offu + nu + 1;                 // nm+1
    int* nbru = offm + nm + 1;                 // E    (movie ids per user)
    int* nbrm = nbru + E;                      // E    (user ids per movie)
    float* stash = (float*)(nbrm + E);         // nm*128 (r_m stable copy)

    const int eg = (E + 255) / 256;

    // ---- build CSR (both directions, shared by both layers) ----
    hipMemsetAsync(cntu, 0, (size_t)(nu + nm) * 4, stream);
    hist_kernel<<<eg, 256, 0, stream>>>(esrc, edst, cntu, cntm, E, nu, nm);
    scan_excl<<<1, 1024, 0, stream>>>(cntu, offu, nu);
    scan_excl<<<1, 1024, 0, stream>>>(cntm, offm, nm);
    fill_kernel<<<eg, 256, 0, stream>>>(esrc, edst, cntu, cntm, nbru, nbrm,
                                        E, nu, nm);

    const int gm = (nm + 15) / 16;
    const int gu = (nu + 15) / 16;

    // ---- layer 1 (reads d_in only; writes r_* into d_out) ----
    fused_update<1><<<gm, 256, 0, stream>>>(
        xu, xm, offm, nbrm, Wl1_um, Wr1_um, b1_um, out_m, nm);
    fused_update<1><<<gu, 256, 0, stream>>>(
        xm, xu, offu, nbru, Wl1_mu, Wr1_mu, b1_mu, out_u, nu);

    // ---- stash r_m, then layer 2 ----
    copy_f32<<<(nm * 128 + 255) / 256, 256, 0, stream>>>(out_m, stash, nm * 128);
    // movie phase: gathers r_u (out_u, untouched), x-rows from stash, writes
    // out_m in-place.
    fused_update<0><<<gm, 256, 0, stream>>>(
        out_u, stash, offm, nbrm, Wl2_um, Wr2_um, b2_um, out_m, nm);
    // user phase: gathers stash (stable), x = out_u rows (LDS-staged before
    // store, each node owned by one block), writes out_u in-place.
    fused_update<0><<<gu, 256, 0, stream>>>(
        stash, out_u, offu, nbru, Wl2_mu, Wr2_mu, b2_mu, out_u, nu);
}

// Round 7
// 903.745 us; speedup vs baseline: 4.4498x; 1.7938x over previous
//
#include <hip/hip_runtime.h>
#include <stdint.h>

typedef unsigned short u16;
typedef unsigned int u32;
typedef __attribute__((ext_vector_type(8))) short short8;   // 8 bf16 (4 VGPRs)
typedef __attribute__((ext_vector_type(4))) float f32x4;    // MFMA acc

__device__ __forceinline__ u16 f2bf(float f) {              // RNE f32->bf16
    u32 x = __float_as_uint(f);
    u32 r = x + 0x7FFFu + ((x >> 16) & 1u);
    return (u16)(r >> 16);
}
__device__ __forceinline__ u32 pack2bf(float a, float b) {
    return (u32)f2bf(a) | ((u32)f2bf(b) << 16);
}

// ================= CSR build (proven in round 6) =================
__global__ __launch_bounds__(256)
void hist_kernel(const int* __restrict__ src, const int* __restrict__ dst,
                 int* __restrict__ cntu, int* __restrict__ cntm,
                 int E, int nu, int nm) {
    int e = blockIdx.x * 256 + threadIdx.x;
    if (e >= E) return;
    int s = src[e], d = dst[e];
    if ((unsigned)s < (unsigned)nu) atomicAdd(&cntu[s], 1);
    if ((unsigned)d < (unsigned)nm) atomicAdd(&cntm[d], 1);
}

__global__ __launch_bounds__(1024)
void scan_excl(int* __restrict__ cnt_cur, int* __restrict__ off, int n) {
    __shared__ int s[1024];
    __shared__ int carry_s;
    const int tid = threadIdx.x;
    if (tid == 0) carry_s = 0;
    __syncthreads();
    const int CH = 1024 * 16;
    for (int chunk = 0; chunk < n; chunk += CH) {
        int base = chunk + tid * 16;
        int v[16];
        int sum = 0;
#pragma unroll
        for (int k = 0; k < 16; ++k) {
            int i = base + k;
            v[k] = (i < n) ? cnt_cur[i] : 0;
            sum += v[k];
        }
        s[tid] = sum;
        __syncthreads();
        for (int d = 1; d < 1024; d <<= 1) {
            int t = (tid >= d) ? s[tid - d] : 0;
            __syncthreads();
            s[tid] += t;
            __syncthreads();
        }
        int run = carry_s + s[tid] - sum;
#pragma unroll
        for (int k = 0; k < 16; ++k) {
            int i = base + k;
            if (i < n) { off[i] = run; cnt_cur[i] = run; }
            run += v[k];
        }
        __syncthreads();
        if (tid == 1023) carry_s += s[1023];
        __syncthreads();
    }
    if (tid == 0) off[n] = carry_s;
}

__global__ __launch_bounds__(256)
void fill_kernel(const int* __restrict__ src, const int* __restrict__ dst,
                 int* __restrict__ curu, int* __restrict__ curm,
                 int* __restrict__ nbru, int* __restrict__ nbrm,
                 int E, int nu, int nm) {
    int e = blockIdx.x * 256 + threadIdx.x;
    if (e >= E) return;
    int s = src[e], d = dst[e];
    if ((unsigned)s >= (unsigned)nu || (unsigned)d >= (unsigned)nm) return;
    int pm = atomicAdd(&curm[d], 1);
    nbrm[pm] = s;
    int pu = atomicAdd(&curu[s], 1);
    nbru[pu] = d;
}

__global__ __launch_bounds__(256)
void copy_f32(const float* __restrict__ src, float* __restrict__ dst, int n) {
    int i = blockIdx.x * 256 + threadIdx.x;
    if (i < n) dst[i] = src[i];
}

// ---- weight prep: W_stack=[Wl;Wr] (256x128 f32) -> bf16, MFMA-B-fragment
// order. For tile t (n-block of 16), step s (K-block of 32), lane l:
// B[k = s*32+(l>>4)*8+j][n = t*16+(l&15)], j=0..7 contiguous.
// Flat layout: frag[(t*8+s)*64 + l][8] -> a wave's load is 1 KB contiguous.
__global__ __launch_bounds__(64)
void wprep(const float* __restrict__ Wl, const float* __restrict__ Wr,
           u16* __restrict__ out) {
    const int bid = blockIdx.x;          // 64 = 8 tiles * 8 steps
    const int t = bid >> 3, s = bid & 7;
    const int lane = threadIdx.x;
    const int n = t * 16 + (lane & 15);
    const int k0 = s * 32 + (lane >> 4) * 8;
    u16 v[8];
#pragma unroll
    for (int j = 0; j < 8; ++j) {
        int k = k0 + j;
        float f = (k < 128) ? Wl[k * 128 + n] : Wr[(k - 128) * 128 + n];
        v[j] = f2bf(f);
    }
    *(short8*)(out + ((size_t)(t * 8 + s) * 64 + lane) * 8) = *(short8*)v;
}

// ================= fused gather-mean + MFMA node update =================
// out = [x + relu](mean_{g in nbr(n)} feat[g] @ Wl + b + x @ Wr)
// Block = 256 thr = 4 waves, 16 nodes. Phase 1: wave w gathers nodes w*4..w*4+3
// (float2/lane, coalesced 512 B rows, 4-way ILP), writes bf16 [mean;x] into
// sVb and f32 x into sX. Phase 2: per wave 2 n-tiles, 8 K-steps of
// v_mfma_f32_16x16x32_bf16; A-frags ds_read_b128 from sVb (row pad +8 ushort
// -> 2-way bank alias = free); B-frags coalesced 1KB global loads from wt.
// In-place safe: x staged to LDS before any store; feat never aliases out.
template <int RELU_RES>
__global__ __launch_bounds__(256)
void fused_update(const float* __restrict__ feat, const float* __restrict__ x,
                  const int* __restrict__ off, const int* __restrict__ nbr,
                  const u16* __restrict__ wt, const float* __restrict__ bias,
                  float* __restrict__ out, int N) {
    __shared__ u32 sVb[16][132];     // bf16 pairs: k<128 mean, k>=128 x; pad 4
    __shared__ float sX[16][130];    // f32 x for epilogue; pad 2
    const int tid = threadIdx.x;
    const int lane = tid & 63;
    const int wave = tid >> 6;
    const int base = blockIdx.x * 16;

    // ---- phase 1: gather-mean ----
    for (int c = 0; c < 4; ++c) {
        const int i = wave * 4 + c;
        const int n = base + i;
        if (n < N) {
            const int b = off[n], e = off[n + 1];
            float a0x = 0.f, a0y = 0.f, a1x = 0.f, a1y = 0.f;
            float a2x = 0.f, a2y = 0.f, a3x = 0.f, a3y = 0.f;
            int t = b;
            for (; t + 3 < e; t += 4) {
                int g0 = nbr[t], g1 = nbr[t + 1], g2 = nbr[t + 2], g3 = nbr[t + 3];
                float2 w0 = ((const float2*)feat)[(size_t)g0 * 64 + lane];
                float2 w1 = ((const float2*)feat)[(size_t)g1 * 64 + lane];
                float2 w2 = ((const float2*)feat)[(size_t)g2 * 64 + lane];
                float2 w3 = ((const float2*)feat)[(size_t)g3 * 64 + lane];
                a0x += w0.x; a0y += w0.y; a1x += w1.x; a1y += w1.y;
                a2x += w2.x; a2y += w2.y; a3x += w3.x; a3y += w3.y;
            }
            for (; t < e; ++t) {
                float2 w = ((const float2*)feat)[(size_t)nbr[t] * 64 + lane];
                a0x += w.x; a0y += w.y;
            }
            const int dg = e - b;
            const float inv = 1.0f / (float)(dg > 1 ? dg : 1);
            const float mx = (a0x + a1x + a2x + a3x) * inv;
            const float my = (a0y + a1y + a2y + a3y) * inv;
            const float2 xv = ((const float2*)x)[(size_t)n * 64 + lane];
            sVb[i][lane] = pack2bf(mx, my);
            sVb[i][64 + lane] = pack2bf(xv.x, xv.y);
            sX[i][2 * lane] = xv.x;
            sX[i][2 * lane + 1] = xv.y;
        } else {
            sVb[i][lane] = 0u;
            sVb[i][64 + lane] = 0u;
            sX[i][2 * lane] = 0.f;
            sX[i][2 * lane + 1] = 0.f;
        }
    }
    __syncthreads();

    // ---- phase 2: MFMA GEMM (16 nodes x 256 K x 128 out) ----
    const int ml = lane & 15;        // A row m / D col n-local
    const int quad = lane >> 4;
    const int t0 = wave * 2, t1 = wave * 2 + 1;
    const u16* sVbu = (const u16*)sVb;  // row stride 264 ushort (528 B)
    const short8* wtp = (const short8*)wt;

    f32x4 acc0 = {0.f, 0.f, 0.f, 0.f};
    f32x4 acc1 = {0.f, 0.f, 0.f, 0.f};
#pragma unroll
    for (int s = 0; s < 8; ++s) {
        short8 a = *(const short8*)(sVbu + (size_t)ml * 264 + s * 32 + quad * 8);
        short8 b0 = wtp[(size_t)(t0 * 8 + s) * 64 + lane];
        short8 b1 = wtp[(size_t)(t1 * 8 + s) * 64 + lane];
        acc0 = __builtin_amdgcn_mfma_f32_16x16x32_bf16(a, b0, acc0, 0, 0, 0);
        acc1 = __builtin_amdgcn_mfma_f32_16x16x32_bf16(a, b1, acc1, 0, 0, 0);
    }

    // ---- epilogue: D[m][n], col=lane&15, row=quad*4+reg ----
    const int n0 = t0 * 16 + ml, n1 = t1 * 16 + ml;
    const float bj0 = bias[n0], bj1 = bias[n1];
#pragma unroll
    for (int r = 0; r < 4; ++r) {
        const int m = quad * 4 + r;
        const int node = base + m;
        if (node < N) {
            float h0 = acc0[r] + bj0;
            float h1 = acc1[r] + bj1;
            float o0 = RELU_RES ? (sX[m][n0] + fmaxf(h0, 0.f)) : h0;
            float o1 = RELU_RES ? (sX[m][n1] + fmaxf(h1, 0.f)) : h1;
            out[(size_t)node * 128 + n0] = o0;
            out[(size_t)node * 128 + n1] = o1;
        }
    }
}

extern "C" void kernel_launch(void* const* d_in, const int* in_sizes, int n_in,
                              void* d_out, int out_size, void* d_ws, size_t ws_size,
                              hipStream_t stream) {
    const int nu = in_sizes[0] / 128;
    const int nm = in_sizes[1] / 128;
    const int E = in_sizes[2];

    const float* xu = (const float*)d_in[0];
    const float* xm = (const float*)d_in[1];
    const int* esrc = (const int*)d_in[2];
    const int* edst = (const int*)d_in[3];
    const float* Wl1_um = (const float*)d_in[4];
    const float* Wr1_um = (const float*)d_in[5];
    const float* Wl1_mu = (const float*)d_in[6];
    const float* Wr1_mu = (const float*)d_in[7];
    const float* Wl2_um = (const float*)d_in[8];
    const float* Wr2_um = (const float*)d_in[9];
    const float* Wl2_mu = (const float*)d_in[10];
    const float* Wr2_mu = (const float*)d_in[11];
    const float* b1_um = (const float*)d_in[12];
    const float* b1_mu = (const float*)d_in[13];
    const float* b2_um = (const float*)d_in[14];
    const float* b2_mu = (const float*)d_in[15];

    float* out_u = (float*)d_out;
    float* out_m = out_u + (size_t)nu * 128;

    // ---- workspace layout (~19.5 MB; >=62 MB available per round 5) ----
    int* cntu = (int*)d_ws;                    // nu
    int* cntm = cntu + nu;                     // nm
    int* offu = cntm + nm;                     // nu+1
    int* offm = offu + nu + 1;                 // nm+1
    int* nbru = offm + nm + 1;                 // E
    int* nbrm = nbru + E;                      // E
    size_t int_bytes = (size_t)(nbrm + E - (int*)d_ws) * 4;
    size_t wt_off = (int_bytes + 63) & ~(size_t)63;   // 16B-align for short8
    u16* wt1_um = (u16*)((char*)d_ws + wt_off);       // 4 stacks x 32768 u16
    u16* wt1_mu = wt1_um + 32768;
    u16* wt2_um = wt1_mu + 32768;
    u16* wt2_mu = wt2_um + 32768;
    float* stash = (float*)((char*)d_ws + wt_off + 4 * 65536);  // nm*128 f32

    const int eg = (E + 255) / 256;

    // ---- weight prep (independent of CSR) ----
    wprep<<<64, 64, 0, stream>>>(Wl1_um, Wr1_um, wt1_um);
    wprep<<<64, 64, 0, stream>>>(Wl1_mu, Wr1_mu, wt1_mu);
    wprep<<<64, 64, 0, stream>>>(Wl2_um, Wr2_um, wt2_um);
    wprep<<<64, 64, 0, stream>>>(Wl2_mu, Wr2_mu, wt2_mu);

    // ---- build CSR (shared by both layers) ----
    hipMemsetAsync(cntu, 0, (size_t)(nu + nm) * 4, stream);
    hist_kernel<<<eg, 256, 0, stream>>>(esrc, edst, cntu, cntm, E, nu, nm);
    scan_excl<<<1, 1024, 0, stream>>>(cntu, offu, nu);
    scan_excl<<<1, 1024, 0, stream>>>(cntm, offm, nm);
    fill_kernel<<<eg, 256, 0, stream>>>(esrc, edst, cntu, cntm, nbru, nbrm,
                                        E, nu, nm);

    const int gm = (nm + 15) / 16;
    const int gu = (nu + 15) / 16;

    // ---- layer 1 (reads d_in only; writes r_* into d_out) ----
    fused_update<1><<<gm, 256, 0, stream>>>(
        xu, xm, offm, nbrm, wt1_um, b1_um, out_m, nm);
    fused_update<1><<<gu, 256, 0, stream>>>(
        xm, xu, offu, nbru, wt1_mu, b1_mu, out_u, nu);

    // ---- stash r_m, then layer 2 ----
    copy_f32<<<(nm * 128 + 255) / 256, 256, 0, stream>>>(out_m, stash, nm * 128);
    // movie phase: gathers r_u (out_u, read-only here), x from stash, writes
    // out_m (not read by anyone in this dispatch).
    fused_update<0><<<gm, 256, 0, stream>>>(
        out_u, stash, offm, nbrm, wt2_um, b2_um, out_m, nm);
    // user phase: gathers stash (stable), x = out_u (LDS-staged before store,
    // each node owned by exactly one block), writes out_u in-place.
    fused_update<0><<<gu, 256, 0, stream>>>(
        stash, out_u, offu, nbru, wt2_mu, b2_mu, out_u, nu);
}